// Round 13
// baseline (1311.306 us; speedup 1.0000x reference)
//
#include <hip/hip_runtime.h>
#include <math.h>

// ---------------- problem dims ----------------
#define E_DIM 512     // embedding dim
#define H_DIM 2048    // hidden
#define G_DIM 8192    // 4*H
#define B_DIM 32      // batch
#define T_DIM 128     // target time
#define S_DIM 128     // source time
#define ENC2  1024    // 2*encoder_hidden
#define SI_DIM 1536   // E + 2*enc (static input)

#define NBLK 256      // persistent blocks (1 per CU)
#define NTHR 512      // 8 waves
#define JT   8        // hidden cols per block
#define KHW  (H_DIM/8)   // 256: W_hh K-slice per wave (8 tiles of 32)
#define KXW  (E_DIM/8)   // 64:  W_ih K-slice per wave (2 tiles of 32)
#define HB   (B_DIM*H_DIM)
#define HPLANE 65536     // ushorts per h plane buffer (64 tiles * 4 * 32 * 8)

// fragment-order plane layout: [tile(32k)][lg(4)][b(32)][8 ushorts]

// ---------------- workspace layout (bytes) ----------------
// xh    ushort [128][16384]  @ 0         (4194304)
// xl    ushort [128][16384]  @ 4194304   (4194304)
// hth   ushort [129][65536]  @ 8388608   (16908288)  rotating per-step buffers
// htl   ushort [129][65536]  @ 25296896  (16908288)
// si    f32 [32][1536]       @ 42205184  (196608)
// flags u32 [256]x16         @ 42401792  (16384)   slot0 = half A, slot1 = half B
// total ~42.4 MB

typedef __bf16 bf16_t;
typedef bf16_t bf16x8 __attribute__((ext_vector_type(8)));
typedef float f32x4 __attribute__((ext_vector_type(4)));
typedef unsigned int u32x4 __attribute__((ext_vector_type(4)));

__device__ __forceinline__ unsigned short f2bf(float x) {
    unsigned u = __float_as_uint(x);
    u += 0x7FFFu + ((u >> 16) & 1u);   // RNE
    return (unsigned short)(u >> 16);
}
__device__ __forceinline__ float bf2f(unsigned short s) {
    return __uint_as_float(((unsigned)s) << 16);
}
__device__ __forceinline__ unsigned pack2(float a, float b) {
    return (unsigned)f2bf(a) | ((unsigned)f2bf(b) << 16);
}
__device__ __forceinline__ f32x4 mfma16(bf16x8 a, bf16x8 b, f32x4 c) {
    return __builtin_amdgcn_mfma_f32_16x16x32_bf16(a, b, c, 0, 0, 0);
}
__device__ __forceinline__ bf16x8 tofrag(u32x4 q) {
    return __builtin_bit_cast(bf16x8, q);
}
__device__ __forceinline__ float sigf(float x) { return 1.f / (1.f + expf(-x)); }

#define OPAQUE(v) asm volatile("" : "+v"(v))
#define ALD(p) __hip_atomic_load((p), __ATOMIC_RELAXED, __HIP_MEMORY_SCOPE_AGENT)
#define AST(p, v) __hip_atomic_store((p), (v), __ATOMIC_RELAXED, __HIP_MEMORY_SCOPE_AGENT)

// W packing: BY-VALUE return of two u32x4
struct WPair { u32x4 hi, lo; };
__device__ __forceinline__ WPair packW(const float* src) {
    float4 w0 = *(const float4*)src;
    float4 w1 = *(const float4*)(src + 16);
    u32x4 qh;
    qh.x = pack2(w0.x, w0.y); qh.y = pack2(w0.z, w0.w);
    qh.z = pack2(w1.x, w1.y); qh.w = pack2(w1.z, w1.w);
    float r0 = w0.x - bf2f((unsigned short)(qh.x & 0xFFFF));
    float r1 = w0.y - bf2f((unsigned short)(qh.x >> 16));
    float r2 = w0.z - bf2f((unsigned short)(qh.y & 0xFFFF));
    float r3 = w0.w - bf2f((unsigned short)(qh.y >> 16));
    float r4 = w1.x - bf2f((unsigned short)(qh.z & 0xFFFF));
    float r5 = w1.y - bf2f((unsigned short)(qh.z >> 16));
    float r6 = w1.z - bf2f((unsigned short)(qh.w & 0xFFFF));
    float r7 = w1.w - bf2f((unsigned short)(qh.w >> 16));
    u32x4 ql;
    ql.x = pack2(r0, r1); ql.y = pack2(r2, r3);
    ql.z = pack2(r4, r5); ql.w = pack2(r6, r7);
    WPair out; out.hi = qh; out.lo = ql;
    return out;
}

// ---- prep: context max-pool, lang embed, h0 -> fragment-order planes (buf 0) ----
__global__ void k_prep(const float* __restrict__ enc_outs, const float* __restrict__ embed,
                       const int* __restrict__ langs, const float* __restrict__ h0,
                       float* __restrict__ si, unsigned short* __restrict__ hth,
                       unsigned short* __restrict__ htl, unsigned int* __restrict__ flags) {
    int tid = blockIdx.x * blockDim.x + threadIdx.x;
    int np = gridDim.x * blockDim.x;
    for (int i = tid; i < NBLK * 16; i += np)
        flags[i] = 0u;
    for (int i = tid; i < B_DIM * ENC2; i += np) {        // context = max over S
        int b = i >> 10, e = i & 1023;
        float m = -3.4e38f;
        for (int s = 0; s < S_DIM; ++s)
            m = fmaxf(m, enc_outs[(s * B_DIM + b) * ENC2 + e]);
        si[b * SI_DIM + E_DIM + e] = m;
    }
    for (int i = tid; i < B_DIM * E_DIM; i += np) {       // lang embedding
        int b = i >> 9, e = i & 511;
        si[b * SI_DIM + e] = embed[(long)langs[b] * E_DIM + e];
    }
    for (int i = tid; i < B_DIM * H_DIM; i += np) {       // h0 into buffer 0
        int b = i >> 11, j = i & 2047;
        float h = h0[i];
        unsigned short hi = f2bf(h);
        unsigned short lo = f2bf(h - bf2f(hi));
        int T = j >> 5, lgp = (j & 15) >> 2, o = (j & 3) + 4 * ((j & 31) >> 4);
        int idx = ((T * 4 + lgp) * 32 + b) * 8 + o;
        hth[idx] = hi;
        htl[idx] = lo;
    }
}

// ---- gather token embeddings -> fragment-order x planes; block r = t*32+b ----
__global__ void k_gather_x(const float* __restrict__ embed, const int* __restrict__ tok,
                           unsigned short* __restrict__ xh, unsigned short* __restrict__ xl) {
    int r = blockIdx.x;
    int t = r >> 5, b = r & 31;
    long row = tok[b * T_DIM + t];
    const float4* src = (const float4*)(embed + row * E_DIM);
    unsigned* xhp = (unsigned*)(xh + (size_t)t * 16384);
    unsigned* xlp = (unsigned*)(xl + (size_t)t * 16384);
    for (int g = threadIdx.x; g < 128; g += blockDim.x) {
        float4 v = src[g];
        unsigned h01 = pack2(v.x, v.y), h23 = pack2(v.z, v.w);
        float rx = v.x - bf2f((unsigned short)(h01 & 0xFFFF));
        float ry = v.y - bf2f((unsigned short)(h01 >> 16));
        float rz = v.z - bf2f((unsigned short)(h23 & 0xFFFF));
        float rw = v.w - bf2f((unsigned short)(h23 >> 16));
        int T = g >> 3, lgp = g & 3, o0 = 4 * ((g & 7) >> 2);
        int u32i = ((T * 4 + lgp) * 32 + b) * 4 + (o0 >> 1);
        uint2 qh; qh.x = h01; qh.y = h23;
        uint2 ql; ql.x = pack2(rx, ry); ql.y = pack2(rz, rw);
        *(uint2*)(xhp + u32i) = qh;
        *(uint2*)(xlp + u32i) = ql;
    }
}

// 6 MFMAs of one 32-k tile for ONE batch-half (A-frags Ah/Al in scope)
#define MFMA6(PH, PL, IT) \
    acc0 = mfma16(Ah, tofrag(PH##0##IT), acc0); \
    acc0 = mfma16(Ah, tofrag(PL##0##IT), acc0); \
    acc0 = mfma16(Al, tofrag(PH##0##IT), acc0); \
    acc1 = mfma16(Ah, tofrag(PH##1##IT), acc1); \
    acc1 = mfma16(Ah, tofrag(PL##1##IT), acc1); \
    acc1 = mfma16(Al, tofrag(PH##1##IT), acc1);

// x tile for one half: cached uint4 loads, fragment-contiguous
#define AX_IT(IT, BOFF) do { \
    const int fb = ((wv * 2 + (IT)) * 4 + lg) * 32 + lr + (BOFF); \
    bf16x8 Ah = __builtin_bit_cast(bf16x8, xh4[fb]); \
    bf16x8 Al = __builtin_bit_cast(bf16x8, xl4[fb]); \
    MFMA6(Xh, Xl, IT) \
} while (0)

// h tile for one half: cached uint4 loads from this step's fresh buffer
#define AH_IT(IT, BOFF) do { \
    const int fb = ((wv * 8 + (IT)) * 4 + lg) * 32 + lr + (BOFF); \
    bf16x8 Ah = __builtin_bit_cast(bf16x8, hh4[fb]); \
    bf16x8 Al = __builtin_bit_cast(bf16x8, hl4[fb]); \
    MFMA6(Wh, Wl, IT) \
} while (0)

#define PK_HH(F, IT) { WPair p = packW(W_hh + (long)rowf##F * H_DIM + (wv * KHW + IT * 32 + 4 * lg)); \
                       Wh##F##IT = p.hi; Wl##F##IT = p.lo; }
#define PK_X(F, IT)  { WPair p = packW(W_ih + (long)rowf##F * 2048 + (wv * KXW + IT * 32 + 4 * lg)); \
                       Xh##F##IT = p.hi; Xl##F##IT = p.lo; }

// one batch-half phase of one timestep
#define HALF_PHASE(BOFF, SLOT, CREG) do { \
    f32x4 acc0 = {}, acc1 = {}; \
    { \
        const uint4* xh4 = (const uint4*)(xh + (size_t)t * 16384); \
        const uint4* xl4 = (const uint4*)(xl + (size_t)t * 16384); \
        AX_IT(0, BOFF); AX_IT(1, BOFF); \
    } \
    if (t > 0) { \
        const unsigned tgt = (unsigned)t; \
        const bool mine = (l < 32); \
        const unsigned int* fp = flags + (size_t)(wv * 32 + (l & 31)) * 16 + (SLOT); \
        for (;;) { \
            unsigned v = mine ? ALD(fp) : tgt; \
            if (__all(v >= tgt)) break; \
            __builtin_amdgcn_s_sleep(1); \
        } \
        __builtin_amdgcn_sched_barrier(0); \
    } \
    { \
        const uint4* hh4 = (const uint4*)(hth + (size_t)t * HPLANE); \
        const uint4* hl4 = (const uint4*)(htl + (size_t)t * HPLANE); \
        AH_IT(0, BOFF); AH_IT(1, BOFF); AH_IT(2, BOFF); AH_IT(3, BOFF); \
        AH_IT(4, BOFF); AH_IT(5, BOFF); AH_IT(6, BOFF); AH_IT(7, BOFF); \
    } \
    red[wv][0][l] = acc0; red[wv][1][l] = acc1; \
    __syncthreads(); \
    float hn = 0.f; \
    if (tid < 128) { \
        const int bh = tid >> 3, jl = tid & 7; \
        const int r_ = bh & 3, q_ = bh >> 2; \
        float gs[4]; \
        _Pragma("unroll") \
        for (int g = 0; g < 4; ++g) { \
            const int l2 = (q_ << 4) | ((g & 1) * 8 + jl); \
            float s = 0.f; \
            _Pragma("unroll") \
            for (int w = 0; w < 8; ++w) s += red[w][g >> 1][l2][r_]; \
            gs[g] = s + sgl[g][(BOFF) + bh][jl]; \
        } \
        float cn = sigf(gs[1]) * (CREG) + sigf(gs[0]) * tanhf(gs[2]); \
        hn = sigf(gs[3]) * tanhf(cn); \
        (CREG) = cn; \
        unsigned short hh_ = f2bf(hn); \
        unsigned short hl_ = f2bf(hn - bf2f(hh_)); \
        unsigned nhh = __shfl_down((unsigned)hh_, 1); \
        unsigned nhl = __shfl_down((unsigned)hl_, 1); \
        if ((jl & 1) == 0) { \
            unsigned* hthn = (unsigned*)(hth + (size_t)(t + 1) * HPLANE); \
            unsigned* htln = (unsigned*)(htl + (size_t)(t + 1) * HPLANE); \
            const int j0 = jb + jl; \
            const int Tt = j0 >> 5, lgp = (j0 & 15) >> 2; \
            const int o_ = (j0 & 3) + 4 * ((j0 & 31) >> 4); \
            const int u32i = ((Tt * 4 + lgp) * 32 + (BOFF) + bh) * 4 + (o_ >> 1); \
            AST(hthn + u32i, (unsigned)hh_ | (nhh << 16)); \
            AST(htln + u32i, (unsigned)hl_ | (nhl << 16)); \
        } \
    } \
    asm volatile("s_waitcnt vmcnt(0)" ::: "memory"); \
    __syncthreads(); \
    if (tid == 0 && t < T_DIM - 1) \
        AST(flags + (size_t)blockIdx.x * 16 + (SLOT), (unsigned)(t + 1)); \
    if (tid < 128) \
        out[(size_t)t * HB + ((BOFF) + (tid >> 3)) * H_DIM + jb + (tid & 7)] = hn; \
} while (0)

// ---- persistent LSTM: batch-split two-phase pipeline ----
__global__ __launch_bounds__(NTHR, 2) void k_lstm(
        const unsigned short* __restrict__ xh, const unsigned short* __restrict__ xl,
        unsigned short* __restrict__ hth, unsigned short* __restrict__ htl,
        const float* __restrict__ si, const float* __restrict__ W_ih,
        const float* __restrict__ W_hh, const float* __restrict__ b_ih,
        const float* __restrict__ b_hh, const float* __restrict__ c0,
        float* __restrict__ out, unsigned int* __restrict__ flags) {
    __shared__ f32x4 red[8][2][64];        // [wave][frag][lane] partials (16 KB)
    __shared__ float sgl[4][B_DIM][JT];    // static gate bias (4 KB)

    const int tid = threadIdx.x;
    const int wv = tid >> 6, l = tid & 63, lr = l & 15, lg = l >> 4;
    const int jb = blockIdx.x * JT;

    // ---- prologue 1: static gate bias sg (fp32, block-local) ----
    {
        int c = tid >> 4, bp = tid & 15;
        int gate = c >> 3, jl = c & 7;
        long grow = (long)(gate * H_DIM + jb + jl);
        const float* wrow = W_ih + grow * 2048 + E_DIM;
        const float* s0 = si + bp * SI_DIM;
        const float* s1 = si + (bp + 16) * SI_DIM;
        float a0 = 0.f, a1 = 0.f;
        for (int k = 0; k < SI_DIM; k += 4) {
            float4 w  = *(const float4*)(wrow + k);
            float4 x0 = *(const float4*)(s0 + k);
            float4 x1 = *(const float4*)(s1 + k);
            a0 += w.x * x0.x + w.y * x0.y + w.z * x0.z + w.w * x0.w;
            a1 += w.x * x1.x + w.y * x1.y + w.z * x1.z + w.w * x1.w;
        }
        float bias = b_ih[grow] + b_hh[grow];
        sgl[gate][bp][jl] = a0 + bias;
        sgl[gate][bp + 16][jl] = a1 + bias;
    }

    // ---- prologue 2: W slices into NAMED register fragments, pinned ----
    const int rowf0 = ((lr >> 3)) * H_DIM + jb + (lr & 7);
    const int rowf1 = (2 + (lr >> 3)) * H_DIM + jb + (lr & 7);

    u32x4 Wh00, Wh01, Wh02, Wh03, Wh04, Wh05, Wh06, Wh07;
    u32x4 Wh10, Wh11, Wh12, Wh13, Wh14, Wh15, Wh16, Wh17;
    u32x4 Wl00, Wl01, Wl02, Wl03, Wl04, Wl05, Wl06, Wl07;
    u32x4 Wl10, Wl11, Wl12, Wl13, Wl14, Wl15, Wl16, Wl17;
    u32x4 Xh00, Xh01, Xh10, Xh11, Xl00, Xl01, Xl10, Xl11;

    PK_HH(0, 0) PK_HH(0, 1) PK_HH(0, 2) PK_HH(0, 3)
    PK_HH(0, 4) PK_HH(0, 5) PK_HH(0, 6) PK_HH(0, 7)
    PK_HH(1, 0) PK_HH(1, 1) PK_HH(1, 2) PK_HH(1, 3)
    PK_HH(1, 4) PK_HH(1, 5) PK_HH(1, 6) PK_HH(1, 7)
    PK_X(0, 0) PK_X(0, 1) PK_X(1, 0) PK_X(1, 1)

    OPAQUE(Wh00); OPAQUE(Wh01); OPAQUE(Wh02); OPAQUE(Wh03);
    OPAQUE(Wh04); OPAQUE(Wh05); OPAQUE(Wh06); OPAQUE(Wh07);
    OPAQUE(Wh10); OPAQUE(Wh11); OPAQUE(Wh12); OPAQUE(Wh13);
    OPAQUE(Wh14); OPAQUE(Wh15); OPAQUE(Wh16); OPAQUE(Wh17);
    OPAQUE(Wl00); OPAQUE(Wl01); OPAQUE(Wl02); OPAQUE(Wl03);
    OPAQUE(Wl04); OPAQUE(Wl05); OPAQUE(Wl06); OPAQUE(Wl07);
    OPAQUE(Wl10); OPAQUE(Wl11); OPAQUE(Wl12); OPAQUE(Wl13);
    OPAQUE(Wl14); OPAQUE(Wl15); OPAQUE(Wl16); OPAQUE(Wl17);
    OPAQUE(Xh00); OPAQUE(Xh01); OPAQUE(Xh10); OPAQUE(Xh11);
    OPAQUE(Xl00); OPAQUE(Xl01); OPAQUE(Xl10); OPAQUE(Xl11);

    // ---- prologue 3: cell state; act thread tid<128 owns (bh, jb+jl) both halves ----
    float cregA = 0.f, cregB = 0.f;
    if (tid < 128) {
        const int bh = tid >> 3, jl = tid & 7;
        cregA = c0[bh * H_DIM + jb + jl];
        cregB = c0[(bh + 16) * H_DIM + jb + jl];
    }

    __syncthreads();   // sgl ready

    // ---- time loop: half A then half B; each half's handshake latency is
    // hidden behind the other half's compute ----
    #pragma unroll 1
    for (int t = 0; t < T_DIM; ++t) {
        HALF_PHASE(0, 0, cregA);
        HALF_PHASE(16, 1, cregB);
    }
}

extern "C" void kernel_launch(void* const* d_in, const int* in_sizes, int n_in,
                              void* d_out, int out_size, void* d_ws, size_t ws_size,
                              hipStream_t stream) {
    const float* embed    = (const float*)d_in[0];
    const float* enc_outs = (const float*)d_in[1];
    const float* h0       = (const float*)d_in[2];
    const float* c0       = (const float*)d_in[3];
    const float* W_ih     = (const float*)d_in[4];
    const float* W_hh     = (const float*)d_in[5];
    const float* b_ih     = (const float*)d_in[6];
    const float* b_hh     = (const float*)d_in[7];
    const int*   tok      = (const int*)d_in[8];
    const int*   langs    = (const int*)d_in[9];
    float* out = (float*)d_out;

    char* ws = (char*)d_ws;
    unsigned short* xh  = (unsigned short*)(ws + 0);
    unsigned short* xl  = (unsigned short*)(ws + 4194304);
    unsigned short* hth = (unsigned short*)(ws + 8388608);
    unsigned short* htl = (unsigned short*)(ws + 25296896);
    float*          si  = (float*)(ws + 42205184);
    unsigned int* flags = (unsigned int*)(ws + 42401792);

    hipLaunchKernelGGL(k_prep, dim3(512), dim3(256), 0, stream,
                       enc_outs, embed, langs, h0, si, hth, htl, flags);
    hipLaunchKernelGGL(k_gather_x, dim3(T_DIM * B_DIM), dim3(128), 0, stream,
                       embed, tok, xh, xl);
    hipLaunchKernelGGL(k_lstm, dim3(NBLK), dim3(NTHR), 0, stream,
                       xh, xl, hth, htl, si, W_ih, W_hh, b_ih, b_hh, c0,
                       out, flags);
}

// Round 14
// 968.780 us; speedup vs baseline: 1.3536x; 1.3536x over previous
//
#include <hip/hip_runtime.h>
#include <math.h>

// ---------------- problem dims ----------------
#define E_DIM 512     // embedding dim
#define H_DIM 2048    // hidden
#define G_DIM 8192    // 4*H
#define B_DIM 32      // batch
#define T_DIM 128     // target time
#define S_DIM 128     // source time
#define ENC2  1024    // 2*encoder_hidden
#define SI_DIM 1536   // E + 2*enc (static input)

#define NBLK 256      // persistent blocks (1 per CU)
#define NTHR 512      // 8 waves
#define JT   8        // hidden cols per block
#define KHW  (H_DIM/8)   // 256: W_hh K-slice per wave (8 tiles of 32)
#define KXW  (E_DIM/8)   // 64:  W_ih K-slice per wave (2 tiles of 32)
#define HB   (B_DIM*H_DIM)
#define HPLANE 65536     // ushorts per h plane buffer (64 tiles * 4 * 32 * 8)

// fragment-order plane layout: [tile(32k)][lg(4)][b(32)][8 ushorts]

// ---------------- workspace layout (bytes) ----------------
// xh    ushort [128][16384]  @ 0         (4194304)
// xl    ushort [128][16384]  @ 4194304   (4194304)
// hth   ushort [129][65536]  @ 8388608   (16908288)  rotating per-step buffers
// htl   ushort [129][65536]  @ 25296896  (16908288)
// si    f32 [32][1536]       @ 42205184  (196608)
// flags u32 [256]x16         @ 42401792  (16384)   slots 0-3 = act waves 0-3
// total ~42.4 MB

typedef __bf16 bf16_t;
typedef bf16_t bf16x8 __attribute__((ext_vector_type(8)));
typedef float f32x4 __attribute__((ext_vector_type(4)));
typedef unsigned int u32x4 __attribute__((ext_vector_type(4)));

__device__ __forceinline__ unsigned short f2bf(float x) {
    unsigned u = __float_as_uint(x);
    u += 0x7FFFu + ((u >> 16) & 1u);   // RNE
    return (unsigned short)(u >> 16);
}
__device__ __forceinline__ float bf2f(unsigned short s) {
    return __uint_as_float(((unsigned)s) << 16);
}
__device__ __forceinline__ unsigned pack2(float a, float b) {
    return (unsigned)f2bf(a) | ((unsigned)f2bf(b) << 16);
}
__device__ __forceinline__ f32x4 mfma16(bf16x8 a, bf16x8 b, f32x4 c) {
    return __builtin_amdgcn_mfma_f32_16x16x32_bf16(a, b, c, 0, 0, 0);
}
__device__ __forceinline__ bf16x8 tofrag(u32x4 q) {
    return __builtin_bit_cast(bf16x8, q);
}
__device__ __forceinline__ float sigf(float x) { return 1.f / (1.f + expf(-x)); }

#define OPAQUE(v) asm volatile("" : "+v"(v))
#define ALD(p) __hip_atomic_load((p), __ATOMIC_RELAXED, __HIP_MEMORY_SCOPE_AGENT)
#define AST(p, v) __hip_atomic_store((p), (v), __ATOMIC_RELAXED, __HIP_MEMORY_SCOPE_AGENT)

// W packing: BY-VALUE return of two u32x4
struct WPair { u32x4 hi, lo; };
__device__ __forceinline__ WPair packW(const float* src) {
    float4 w0 = *(const float4*)src;
    float4 w1 = *(const float4*)(src + 16);
    u32x4 qh;
    qh.x = pack2(w0.x, w0.y); qh.y = pack2(w0.z, w0.w);
    qh.z = pack2(w1.x, w1.y); qh.w = pack2(w1.z, w1.w);
    float r0 = w0.x - bf2f((unsigned short)(qh.x & 0xFFFF));
    float r1 = w0.y - bf2f((unsigned short)(qh.x >> 16));
    float r2 = w0.z - bf2f((unsigned short)(qh.y & 0xFFFF));
    float r3 = w0.w - bf2f((unsigned short)(qh.y >> 16));
    float r4 = w1.x - bf2f((unsigned short)(qh.z & 0xFFFF));
    float r5 = w1.y - bf2f((unsigned short)(qh.z >> 16));
    float r6 = w1.z - bf2f((unsigned short)(qh.w & 0xFFFF));
    float r7 = w1.w - bf2f((unsigned short)(qh.w >> 16));
    u32x4 ql;
    ql.x = pack2(r0, r1); ql.y = pack2(r2, r3);
    ql.z = pack2(r4, r5); ql.w = pack2(r6, r7);
    WPair out; out.hi = qh; out.lo = ql;
    return out;
}

// ---- prep: context max-pool, lang embed, h0 -> fragment-order planes (buf 0) ----
__global__ void k_prep(const float* __restrict__ enc_outs, const float* __restrict__ embed,
                       const int* __restrict__ langs, const float* __restrict__ h0,
                       float* __restrict__ si, unsigned short* __restrict__ hth,
                       unsigned short* __restrict__ htl, unsigned int* __restrict__ flags) {
    int tid = blockIdx.x * blockDim.x + threadIdx.x;
    int np = gridDim.x * blockDim.x;
    for (int i = tid; i < NBLK * 16; i += np)
        flags[i] = 0u;
    for (int i = tid; i < B_DIM * ENC2; i += np) {        // context = max over S
        int b = i >> 10, e = i & 1023;
        float m = -3.4e38f;
        for (int s = 0; s < S_DIM; ++s)
            m = fmaxf(m, enc_outs[(s * B_DIM + b) * ENC2 + e]);
        si[b * SI_DIM + E_DIM + e] = m;
    }
    for (int i = tid; i < B_DIM * E_DIM; i += np) {       // lang embedding
        int b = i >> 9, e = i & 511;
        si[b * SI_DIM + e] = embed[(long)langs[b] * E_DIM + e];
    }
    for (int i = tid; i < B_DIM * H_DIM; i += np) {       // h0 into buffer 0
        int b = i >> 11, j = i & 2047;
        float h = h0[i];
        unsigned short hi = f2bf(h);
        unsigned short lo = f2bf(h - bf2f(hi));
        int T = j >> 5, lgp = (j & 15) >> 2, o = (j & 3) + 4 * ((j & 31) >> 4);
        int idx = ((T * 4 + lgp) * 32 + b) * 8 + o;
        hth[idx] = hi;
        htl[idx] = lo;
    }
}

// ---- gather token embeddings -> fragment-order x planes; block r = t*32+b ----
__global__ void k_gather_x(const float* __restrict__ embed, const int* __restrict__ tok,
                           unsigned short* __restrict__ xh, unsigned short* __restrict__ xl) {
    int r = blockIdx.x;
    int t = r >> 5, b = r & 31;
    long row = tok[b * T_DIM + t];
    const float4* src = (const float4*)(embed + row * E_DIM);
    unsigned* xhp = (unsigned*)(xh + (size_t)t * 16384);
    unsigned* xlp = (unsigned*)(xl + (size_t)t * 16384);
    for (int g = threadIdx.x; g < 128; g += blockDim.x) {
        float4 v = src[g];
        unsigned h01 = pack2(v.x, v.y), h23 = pack2(v.z, v.w);
        float rx = v.x - bf2f((unsigned short)(h01 & 0xFFFF));
        float ry = v.y - bf2f((unsigned short)(h01 >> 16));
        float rz = v.z - bf2f((unsigned short)(h23 & 0xFFFF));
        float rw = v.w - bf2f((unsigned short)(h23 >> 16));
        int T = g >> 3, lgp = g & 3, o0 = 4 * ((g & 7) >> 2);
        int u32i = ((T * 4 + lgp) * 32 + b) * 4 + (o0 >> 1);
        uint2 qh; qh.x = h01; qh.y = h23;
        uint2 ql; ql.x = pack2(rx, ry); ql.y = pack2(rz, rw);
        *(uint2*)(xhp + u32i) = qh;
        *(uint2*)(xlp + u32i) = ql;
    }
}

// 12 MFMAs of one 32-k tile against fragment set PFX{h,l}{0,1}IT
#define MFMA12(PH, PL, IT) \
    acc00 = mfma16(Ah0, tofrag(PH##0##IT), acc00); \
    acc00 = mfma16(Ah0, tofrag(PL##0##IT), acc00); \
    acc00 = mfma16(Al0, tofrag(PH##0##IT), acc00); \
    acc01 = mfma16(Ah1, tofrag(PH##0##IT), acc01); \
    acc01 = mfma16(Ah1, tofrag(PL##0##IT), acc01); \
    acc01 = mfma16(Al1, tofrag(PH##0##IT), acc01); \
    acc10 = mfma16(Ah0, tofrag(PH##1##IT), acc10); \
    acc10 = mfma16(Ah0, tofrag(PL##1##IT), acc10); \
    acc10 = mfma16(Al0, tofrag(PH##1##IT), acc10); \
    acc11 = mfma16(Ah1, tofrag(PH##1##IT), acc11); \
    acc11 = mfma16(Ah1, tofrag(PL##1##IT), acc11); \
    acc11 = mfma16(Al1, tofrag(PH##1##IT), acc11);

// x tile: cached uint4 loads, fragment-contiguous, zero unpack
#define AX_IT(IT) do { \
    const int fb = ((wv * 2 + (IT)) * 4 + lg) * 32 + lr; \
    bf16x8 Ah0 = __builtin_bit_cast(bf16x8, xh4[fb]); \
    bf16x8 Ah1 = __builtin_bit_cast(bf16x8, xh4[fb + 16]); \
    bf16x8 Al0 = __builtin_bit_cast(bf16x8, xl4[fb]); \
    bf16x8 Al1 = __builtin_bit_cast(bf16x8, xl4[fb + 16]); \
    MFMA12(Xh, Xl, IT) \
} while (0)

// h tile: cached uint4 loads from this step's FRESH buffer (rotating buffers:
// addresses never cached before this step -> L2 can't be stale, XCD blocks share)
#define AH_IT(IT) do { \
    const int fb = ((wv * 8 + (IT)) * 4 + lg) * 32 + lr; \
    bf16x8 Ah0 = __builtin_bit_cast(bf16x8, hh4[fb]); \
    bf16x8 Ah1 = __builtin_bit_cast(bf16x8, hh4[fb + 16]); \
    bf16x8 Al0 = __builtin_bit_cast(bf16x8, hl4[fb]); \
    bf16x8 Al1 = __builtin_bit_cast(bf16x8, hl4[fb + 16]); \
    MFMA12(Wh, Wl, IT) \
} while (0)

#define PK_HH(F, IT) { WPair p = packW(W_hh + (long)rowf##F * H_DIM + (wv * KHW + IT * 32 + 4 * lg)); \
                       Wh##F##IT = p.hi; Wl##F##IT = p.lo; }
#define PK_X(F, IT)  { WPair p = packW(W_ih + (long)rowf##F * 2048 + (wv * KXW + IT * 32 + 4 * lg)); \
                       Xh##F##IT = p.hi; Xl##F##IT = p.lo; }

// ---- persistent LSTM: W in registers, rotating h buffers, offloaded tail ----
__global__ __launch_bounds__(NTHR, 2) void k_lstm(
        const unsigned short* __restrict__ xh, const unsigned short* __restrict__ xl,
        unsigned short* __restrict__ hth, unsigned short* __restrict__ htl,
        const float* __restrict__ si, const float* __restrict__ W_ih,
        const float* __restrict__ W_hh, const float* __restrict__ b_ih,
        const float* __restrict__ b_hh, const float* __restrict__ c0,
        float* __restrict__ out, unsigned int* __restrict__ flags) {
    __shared__ f32x4 red[8][2][2][64];     // [wave][frag][Ahalf][lane] partials (32 KB)
    __shared__ float sgl[4][B_DIM][JT];    // static gate bias (4 KB)

    const int tid = threadIdx.x;
    const int wv = tid >> 6, l = tid & 63, lr = l & 15, lg = l >> 4;
    const int jb = blockIdx.x * JT;

    // ---- prologue 1: static gate bias sg (fp32, block-local) ----
    {
        int c = tid >> 4, bp = tid & 15;
        int gate = c >> 3, jl = c & 7;
        long grow = (long)(gate * H_DIM + jb + jl);
        const float* wrow = W_ih + grow * 2048 + E_DIM;
        const float* s0 = si + bp * SI_DIM;
        const float* s1 = si + (bp + 16) * SI_DIM;
        float a0 = 0.f, a1 = 0.f;
        for (int k = 0; k < SI_DIM; k += 4) {
            float4 w  = *(const float4*)(wrow + k);
            float4 x0 = *(const float4*)(s0 + k);
            float4 x1 = *(const float4*)(s1 + k);
            a0 += w.x * x0.x + w.y * x0.y + w.z * x0.z + w.w * x0.w;
            a1 += w.x * x1.x + w.y * x1.y + w.z * x1.z + w.w * x1.w;
        }
        float bias = b_ih[grow] + b_hh[grow];
        sgl[gate][bp][jl] = a0 + bias;
        sgl[gate][bp + 16][jl] = a1 + bias;
    }

    // ---- prologue 2: W slices into NAMED register fragments, pinned ----
    const int rowf0 = ((lr >> 3)) * H_DIM + jb + (lr & 7);
    const int rowf1 = (2 + (lr >> 3)) * H_DIM + jb + (lr & 7);

    u32x4 Wh00, Wh01, Wh02, Wh03, Wh04, Wh05, Wh06, Wh07;
    u32x4 Wh10, Wh11, Wh12, Wh13, Wh14, Wh15, Wh16, Wh17;
    u32x4 Wl00, Wl01, Wl02, Wl03, Wl04, Wl05, Wl06, Wl07;
    u32x4 Wl10, Wl11, Wl12, Wl13, Wl14, Wl15, Wl16, Wl17;
    u32x4 Xh00, Xh01, Xh10, Xh11, Xl00, Xl01, Xl10, Xl11;

    PK_HH(0, 0) PK_HH(0, 1) PK_HH(0, 2) PK_HH(0, 3)
    PK_HH(0, 4) PK_HH(0, 5) PK_HH(0, 6) PK_HH(0, 7)
    PK_HH(1, 0) PK_HH(1, 1) PK_HH(1, 2) PK_HH(1, 3)
    PK_HH(1, 4) PK_HH(1, 5) PK_HH(1, 6) PK_HH(1, 7)
    PK_X(0, 0) PK_X(0, 1) PK_X(1, 0) PK_X(1, 1)

    OPAQUE(Wh00); OPAQUE(Wh01); OPAQUE(Wh02); OPAQUE(Wh03);
    OPAQUE(Wh04); OPAQUE(Wh05); OPAQUE(Wh06); OPAQUE(Wh07);
    OPAQUE(Wh10); OPAQUE(Wh11); OPAQUE(Wh12); OPAQUE(Wh13);
    OPAQUE(Wh14); OPAQUE(Wh15); OPAQUE(Wh16); OPAQUE(Wh17);
    OPAQUE(Wl00); OPAQUE(Wl01); OPAQUE(Wl02); OPAQUE(Wl03);
    OPAQUE(Wl04); OPAQUE(Wl05); OPAQUE(Wl06); OPAQUE(Wl07);
    OPAQUE(Wl10); OPAQUE(Wl11); OPAQUE(Wl12); OPAQUE(Wl13);
    OPAQUE(Wl14); OPAQUE(Wl15); OPAQUE(Wl16); OPAQUE(Wl17);
    OPAQUE(Xh00); OPAQUE(Xh01); OPAQUE(Xh10); OPAQUE(Xh11);
    OPAQUE(Xl00); OPAQUE(Xl01); OPAQUE(Xl10); OPAQUE(Xl11);

    // ---- prologue 3: cell state; threads<256 (waves 0-3) own cell (ab, jb+ajl) ----
    const int ab = tid >> 3, ajl = tid & 7;
    float creg = 0.f;
    if (tid < 256) creg = c0[ab * H_DIM + jb + ajl];

    __syncthreads();   // sgl ready

    // ---- time loop ----
    #pragma unroll 1
    for (int t = 0; t < T_DIM; ++t) {
        f32x4 acc00 = {}, acc01 = {}, acc10 = {}, acc11 = {};  // [frag][Ahalf]

        // input term FIRST (cached, hot in L2; overlaps other blocks' tails)
        {
            const uint4* xh4 = (const uint4*)(xh + (size_t)t * 16384);
            const uint4* xl4 = (const uint4*)(xl + (size_t)t * 16384);
            AX_IT(0); AX_IT(1);
        }

        // per-wave partial wait: wave wv needs h-units from blocks wv*32..wv*32+31;
        // each block posts 4 flags (one per act wave). 2 ALDs cover slots 0-3.
        if (t > 0) {
            const unsigned tgt = (unsigned)t;
            const unsigned int* fp =
                flags + (size_t)(wv * 32 + (l & 31)) * 16 + (l >> 5);
            for (;;) {
                unsigned v0 = ALD(fp);
                unsigned v1 = ALD(fp + 2);
                if (__all(v0 >= tgt && v1 >= tgt)) break;
                __builtin_amdgcn_s_sleep(1);
            }
            __builtin_amdgcn_sched_barrier(0);   // no h-load hoisting above wait
        }

        // recurrent term: cached uint4 loads from this step's fresh buffer
        {
            const uint4* hh4 = (const uint4*)(hth + (size_t)t * HPLANE);
            const uint4* hl4 = (const uint4*)(htl + (size_t)t * HPLANE);
            AH_IT(0); AH_IT(1); AH_IT(2); AH_IT(3);
            AH_IT(4); AH_IT(5); AH_IT(6); AH_IT(7);
        }

        // publish partials
        red[wv][0][0][l] = acc00; red[wv][0][1][l] = acc01;
        red[wv][1][0][l] = acc10; red[wv][1][1][l] = acc11;
        __syncthreads();   // sync1: red complete

        // act waves gather gate sums from red into REGISTERS (conflict-free:
        // lanes 0-31 hit 32 distinct banks, lanes 32-63 free 2-way repeat)
        float gs[4];
        if (tid < 256) {
            const int m = ab >> 4, r = ab & 3, q = (ab & 15) >> 2;
            #pragma unroll
            for (int g = 0; g < 4; ++g) {
                const int l2 = (q << 4) | ((g & 1) * 8 + ajl);
                float s = 0.f;
                #pragma unroll
                for (int w = 0; w < 8; ++w)
                    s += red[w][g >> 1][m][l2][r];
                gs[g] = s + sgl[g][ab][ajl];
            }
        }
        __syncthreads();   // sync2: red free; waves 4-7 sprint to step t+1

        // producer tail: ONLY waves 0-3. Waves 4-7 are already issuing the
        // next step's x-term and polling (their poll absorbs this tail).
        if (tid < 256) {
            float cn = sigf(gs[1]) * creg + sigf(gs[0]) * tanhf(gs[2]);
            float hn = sigf(gs[3]) * tanhf(cn);
            creg = cn;
            unsigned short hh = f2bf(hn);
            unsigned short hl = f2bf(hn - bf2f(hh));
            unsigned nhh = __shfl_down((unsigned)hh, 1);
            unsigned nhl = __shfl_down((unsigned)hl, 1);
            if ((ajl & 1) == 0) {   // even-jl lane stores the packed j-pair
                unsigned* hthn = (unsigned*)(hth + (size_t)(t + 1) * HPLANE);
                unsigned* htln = (unsigned*)(htl + (size_t)(t + 1) * HPLANE);
                int j0 = jb + ajl;
                int T = j0 >> 5, lgp = (j0 & 15) >> 2;
                int o = (j0 & 3) + 4 * ((j0 & 31) >> 4);
                int u32i = ((T * 4 + lgp) * 32 + ab) * 4 + (o >> 1);
                AST(hthn + u32i, (unsigned)hh | (nhh << 16));
                AST(htln + u32i, (unsigned)hl | (nhl << 16));
            }
            // drain THIS wave's h stores to LLC, then post this wave's flag
            asm volatile("s_waitcnt vmcnt(0)" ::: "memory");
            if (l == 0 && t < T_DIM - 1)
                AST(flags + (size_t)blockIdx.x * 16 + wv, (unsigned)(t + 1));
            // out store AFTER the flag — off the critical path
            out[(size_t)t * HB + ab * H_DIM + jb + ajl] = hn;
        }
    }
}

extern "C" void kernel_launch(void* const* d_in, const int* in_sizes, int n_in,
                              void* d_out, int out_size, void* d_ws, size_t ws_size,
                              hipStream_t stream) {
    const float* embed    = (const float*)d_in[0];
    const float* enc_outs = (const float*)d_in[1];
    const float* h0       = (const float*)d_in[2];
    const float* c0       = (const float*)d_in[3];
    const float* W_ih     = (const float*)d_in[4];
    const float* W_hh     = (const float*)d_in[5];
    const float* b_ih     = (const float*)d_in[6];
    const float* b_hh     = (const float*)d_in[7];
    const int*   tok      = (const int*)d_in[8];
    const int*   langs    = (const int*)d_in[9];
    float* out = (float*)d_out;

    char* ws = (char*)d_ws;
    unsigned short* xh  = (unsigned short*)(ws + 0);
    unsigned short* xl  = (unsigned short*)(ws + 4194304);
    unsigned short* hth = (unsigned short*)(ws + 8388608);
    unsigned short* htl = (unsigned short*)(ws + 25296896);
    float*          si  = (float*)(ws + 42205184);
    unsigned int* flags = (unsigned int*)(ws + 42401792);

    hipLaunchKernelGGL(k_prep, dim3(512), dim3(256), 0, stream,
                       enc_outs, embed, langs, h0, si, hth, htl, flags);
    hipLaunchKernelGGL(k_gather_x, dim3(T_DIM * B_DIM), dim3(128), 0, stream,
                       embed, tok, xh, xl);
    hipLaunchKernelGGL(k_lstm, dim3(NBLK), dim3(NTHR), 0, stream,
                       xh, xl, hth, htl, si, W_ih, W_hh, b_ih, b_hh, c0,
                       out, flags);
}